// Round 17
// baseline (548.429 us; speedup 1.0000x reference)
//
#include <hip/hip_runtime.h>
#include <hip/hip_bf16.h>

#define TT 2048
#define BB 4
#define HH 4
#define DD 1024

using bf16x8 = __attribute__((ext_vector_type(8))) short;
using f32x4  = __attribute__((ext_vector_type(4))) float;

__device__ __forceinline__ float wave_sum(float x) {
#pragma unroll
  for (int off = 32; off >= 1; off >>= 1) x += __shfl_xor(x, off);
  return x;
}

__device__ __forceinline__ float siluf(float x) {
  return x / (1.f + expf(-x));
}

__device__ __forceinline__ unsigned short f2bf(float f) {
  unsigned u = __float_as_uint(f);
  u = (u + 0x7fffu + ((u >> 16) & 1u)) >> 16;
  return (unsigned short)u;
}
__device__ __forceinline__ float bf2f(unsigned short b) {
  return __uint_as_float(((unsigned)b) << 16);
}
__device__ __forceinline__ unsigned pack2(float a, float b) {
  return ((unsigned)f2bf(a)) | (((unsigned)f2bf(b)) << 16);
}

// async global->LDS, 16B per lane; dest = lds base + lane*16 (linear)
__device__ __forceinline__ void gload_lds16(const void* g, void* l) {
  __builtin_amdgcn_global_load_lds(
      (const __attribute__((address_space(1))) unsigned int*)g,
      (__attribute__((address_space(3))) unsigned int*)l, 16, 0, 0);
}

// LDS-only barrier: drain ds ops, raw barrier, pin scheduler.
#define LBAR()                                              \
  do {                                                      \
    asm volatile("s_waitcnt lgkmcnt(0)" ::: "memory");      \
    __builtin_amdgcn_s_barrier();                           \
    __builtin_amdgcn_sched_barrier(0);                      \
  } while (0)

// ---------------- bf16 MFMA GEMM: C[M,N] = A[M,K] @ B[K,N], Bt is [N][K] ----
__global__ __launch_bounds__(256) void gemm_bt(const unsigned short* __restrict__ A,
                                               const unsigned short* __restrict__ Bt,
                                               float* __restrict__ C,
                                               int M, int N, int K) {
  __shared__ unsigned short As[128 * 64];
  __shared__ unsigned short Bs[128 * 64];
  const int tid = threadIdx.x;
  const int l = tid & 63;
  const int w = tid >> 6;
  const int wm = w >> 1, wn = w & 1;
  const int bid = blockIdx.x;
  const int nt = N >> 7;
  const int swz = (bid & 7) * ((int)gridDim.x >> 3) + (bid >> 3);
  const int m0 = (swz / nt) * 128, n0 = (swz % nt) * 128;

  f32x4 acc[4][4];
#pragma unroll
  for (int i = 0; i < 4; ++i)
#pragma unroll
    for (int j = 0; j < 4; ++j) acc[i][j] = (f32x4){0.f, 0.f, 0.f, 0.f};

  size_t asrc[4], bsrc[4];
  int ldst[4];
#pragma unroll
  for (int it = 0; it < 4; ++it) {
    int chunk = (it * 4 + w) * 64 + l;
    int row = chunk >> 3, s = chunk & 7;
    size_t soff = (size_t)row * K + ((s ^ (row & 7)) << 3);
    asrc[it] = (size_t)m0 * K + soff;
    bsrc[it] = (size_t)n0 * K + soff;
    ldst[it] = chunk * 8;
  }
  int ra_off[2][4], rb_off[2][4];
#pragma unroll
  for (int kh = 0; kh < 2; ++kh)
#pragma unroll
    for (int f = 0; f < 4; ++f) {
      int rowA = wm * 64 + f * 16 + (l & 15);
      ra_off[kh][f] = rowA * 128 + (((kh * 4 + (l >> 4)) ^ (rowA & 7)) << 4);
      int rowB = wn * 64 + f * 16 + (l & 15);
      rb_off[kh][f] = rowB * 128 + (((kh * 4 + (l >> 4)) ^ (rowB & 7)) << 4);
    }

  for (int k0 = 0; k0 < K; k0 += 64) {
    __syncthreads();
#pragma unroll
    for (int it = 0; it < 4; ++it) {
      gload_lds16(A + asrc[it] + k0, As + ldst[it] - l * 8);
      gload_lds16(Bt + bsrc[it] + k0, Bs + ldst[it] - l * 8);
    }
    __syncthreads();
#pragma unroll
    for (int kh = 0; kh < 2; ++kh) {
      bf16x8 af[4], bfv[4];
#pragma unroll
      for (int f = 0; f < 4; ++f) {
        af[f] = *(const bf16x8*)((const char*)As + ra_off[kh][f]);
        bfv[f] = *(const bf16x8*)((const char*)Bs + rb_off[kh][f]);
      }
#pragma unroll
      for (int i = 0; i < 4; ++i)
#pragma unroll
        for (int j = 0; j < 4; ++j)
          acc[i][j] = __builtin_amdgcn_mfma_f32_16x16x32_bf16(af[i], bfv[j],
                                                              acc[i][j], 0, 0, 0);
    }
  }
  const int cn = n0 + wn * 64 + (l & 15);
  const int rbase = m0 + wm * 64 + ((l >> 4) << 2);
#pragma unroll
  for (int i = 0; i < 4; ++i)
#pragma unroll
    for (int j = 0; j < 4; ++j)
#pragma unroll
      for (int r = 0; r < 4; ++r)
        C[(size_t)(rbase + i * 16 + r) * N + cn + j * 16] = acc[i][j][r];
}

// ------------- split-bf16 3-term GEMM (fp32-accurate): C = Ah@Bh+Al@Bh+Ah@Bl
__global__ __launch_bounds__(256) void gemm_bt3(const unsigned short* __restrict__ Ah,
                                                const unsigned short* __restrict__ Al,
                                                const unsigned short* __restrict__ Bh,
                                                const unsigned short* __restrict__ Bl,
                                                float* __restrict__ C,
                                                int M, int N, int K) {
  __shared__ unsigned short Ash[128 * 64];
  __shared__ unsigned short Asl[128 * 64];
  __shared__ unsigned short Bsh[128 * 64];
  __shared__ unsigned short Bsl[128 * 64];
  const int tid = threadIdx.x;
  const int l = tid & 63;
  const int w = tid >> 6;
  const int wm = w >> 1, wn = w & 1;
  const int bid = blockIdx.x;
  const int nt = N >> 7;
  const int swz = (bid & 7) * ((int)gridDim.x >> 3) + (bid >> 3);
  const int m0 = (swz / nt) * 128, n0 = (swz % nt) * 128;

  f32x4 acc[4][4];
#pragma unroll
  for (int i = 0; i < 4; ++i)
#pragma unroll
    for (int j = 0; j < 4; ++j) acc[i][j] = (f32x4){0.f, 0.f, 0.f, 0.f};

  size_t asrc[4], bsrc[4];
  int ldst[4];
#pragma unroll
  for (int it = 0; it < 4; ++it) {
    int chunk = (it * 4 + w) * 64 + l;
    int row = chunk >> 3, s = chunk & 7;
    size_t soff = (size_t)row * K + ((s ^ (row & 7)) << 3);
    asrc[it] = (size_t)m0 * K + soff;
    bsrc[it] = (size_t)n0 * K + soff;
    ldst[it] = chunk * 8;
  }
  int ra_off[2][4], rb_off[2][4];
#pragma unroll
  for (int kh = 0; kh < 2; ++kh)
#pragma unroll
    for (int f = 0; f < 4; ++f) {
      int rowA = wm * 64 + f * 16 + (l & 15);
      ra_off[kh][f] = rowA * 128 + (((kh * 4 + (l >> 4)) ^ (rowA & 7)) << 4);
      int rowB = wn * 64 + f * 16 + (l & 15);
      rb_off[kh][f] = rowB * 128 + (((kh * 4 + (l >> 4)) ^ (rowB & 7)) << 4);
    }

  for (int k0 = 0; k0 < K; k0 += 64) {
    __syncthreads();
#pragma unroll
    for (int it = 0; it < 4; ++it) {
      gload_lds16(Ah + asrc[it] + k0, Ash + ldst[it] - l * 8);
      gload_lds16(Al + asrc[it] + k0, Asl + ldst[it] - l * 8);
      gload_lds16(Bh + bsrc[it] + k0, Bsh + ldst[it] - l * 8);
      gload_lds16(Bl + bsrc[it] + k0, Bsl + ldst[it] - l * 8);
    }
    __syncthreads();
#pragma unroll
    for (int kh = 0; kh < 2; ++kh) {
      bf16x8 afh[4], bfh[4], tmp[4];
#pragma unroll
      for (int f = 0; f < 4; ++f) {
        afh[f] = *(const bf16x8*)((const char*)Ash + ra_off[kh][f]);
        bfh[f] = *(const bf16x8*)((const char*)Bsh + rb_off[kh][f]);
      }
#pragma unroll
      for (int i = 0; i < 4; ++i)
#pragma unroll
        for (int j = 0; j < 4; ++j)
          acc[i][j] = __builtin_amdgcn_mfma_f32_16x16x32_bf16(afh[i], bfh[j],
                                                              acc[i][j], 0, 0, 0);
#pragma unroll
      for (int f = 0; f < 4; ++f)
        tmp[f] = *(const bf16x8*)((const char*)Asl + ra_off[kh][f]);
#pragma unroll
      for (int i = 0; i < 4; ++i)
#pragma unroll
        for (int j = 0; j < 4; ++j)
          acc[i][j] = __builtin_amdgcn_mfma_f32_16x16x32_bf16(tmp[i], bfh[j],
                                                              acc[i][j], 0, 0, 0);
#pragma unroll
      for (int f = 0; f < 4; ++f)
        tmp[f] = *(const bf16x8*)((const char*)Bsl + rb_off[kh][f]);
#pragma unroll
      for (int i = 0; i < 4; ++i)
#pragma unroll
        for (int j = 0; j < 4; ++j)
          acc[i][j] = __builtin_amdgcn_mfma_f32_16x16x32_bf16(afh[i], tmp[j],
                                                              acc[i][j], 0, 0, 0);
    }
  }
  const int cn = n0 + wn * 64 + (l & 15);
  const int rbase = m0 + wm * 64 + ((l >> 4) << 2);
#pragma unroll
  for (int i = 0; i < 4; ++i)
#pragma unroll
    for (int j = 0; j < 4; ++j)
#pragma unroll
      for (int r = 0; r < 4; ++r)
        C[(size_t)(rbase + i * 16 + r) * N + cn + j * 16] = acc[i][j][r];
}

// ---------------- casts ----------------
__global__ __launch_bounds__(256) void cast2_bf16_kernel(const float* __restrict__ in,
                                                         unsigned short* __restrict__ hi,
                                                         unsigned short* __restrict__ lo) {
  const size_t i = ((size_t)blockIdx.x * 256 + threadIdx.x) * 4;
  float4 x = *(const float4*)(in + i);
  ushort4 h4, l4;
  h4.x = f2bf(x.x); l4.x = f2bf(x.x - bf2f(h4.x));
  h4.y = f2bf(x.y); l4.y = f2bf(x.y - bf2f(h4.y));
  h4.z = f2bf(x.z); l4.z = f2bf(x.z - bf2f(h4.z));
  h4.w = f2bf(x.w); l4.w = f2bf(x.w - bf2f(h4.w));
  *(ushort4*)(hi + i) = h4;
  *(ushort4*)(lo + i) = l4;
}

// fused weight transpose+cast: which=0..3 -> Wq/Wk/Wv/Wo; which=4 -> Wr hi/lo.
__global__ __launch_bounds__(256) void tcast_all_kernel(
    const float* __restrict__ Wq, const float* __restrict__ Wk,
    const float* __restrict__ Wv, const float* __restrict__ Wo,
    const float* __restrict__ Wr, unsigned short* __restrict__ WT0,
    unsigned short* __restrict__ WTrH, unsigned short* __restrict__ WTrL) {
  __shared__ float tile[32][33];
  const int which = blockIdx.x >> 10;
  const int bid = blockIdx.x & 1023;
  const int bx = bid & 31, by = bid >> 5;
  const float* W = (which == 0) ? Wq
                   : (which == 1) ? Wk
                   : (which == 2) ? Wv
                   : (which == 3) ? Wo
                                  : Wr;
  const int tx = threadIdx.x, ty = threadIdx.y;
  const int c0 = bx * 32, r0 = by * 32;
#pragma unroll
  for (int i = 0; i < 4; ++i)
    tile[ty + 8 * i][tx] = W[(size_t)(r0 + ty + 8 * i) * 1024 + c0 + tx];
  __syncthreads();
  if (which < 4) {
    unsigned short* WT = WT0 + (size_t)which * 1048576;
#pragma unroll
    for (int i = 0; i < 4; ++i)
      WT[(size_t)(c0 + ty + 8 * i) * 1024 + r0 + tx] = f2bf(tile[tx][ty + 8 * i]);
  } else {
#pragma unroll
    for (int i = 0; i < 4; ++i) {
      float x = tile[tx][ty + 8 * i];
      unsigned short h = f2bf(x);
      WTrH[(size_t)(c0 + ty + 8 * i) * 1024 + r0 + tx] = h;
      WTrL[(size_t)(c0 + ty + 8 * i) * 1024 + r0 + tx] = f2bf(x - bf2f(h));
    }
  }
}

// ---- fused routing + phase A: per (bh,chunk) block. Preamble does routing
// for its 64 rows (verbatim per-wave logic, results in LDS); stage-0 applies
// masks/norms inline in identical fp32 op order (bit-identical numerics).
__global__ __launch_bounds__(256) void phaseA_kernel(
    const float* __restrict__ hidden, const float* __restrict__ Wa,
    const float* __restrict__ Wb, const float* __restrict__ dt,
    const float* __restrict__ rproj, const float* __restrict__ qkv,
    float* __restrict__ expcG, float* __restrict__ betaT,
    unsigned short* __restrict__ TinvB, unsigned short* __restrict__ AB,
    unsigned short* __restrict__ Wg, unsigned short* __restrict__ Qg,
    unsigned short* __restrict__ XTg) {
  __shared__ unsigned short XB[64 * 256];
  __shared__ unsigned short QW[128 * 256];
  __shared__ float Mb[64 * 68];
  __shared__ int widxL[64][4];
  __shared__ float wgL[64][4], wkfacL[64][4], knL[64], qnL[64], betaL[64];
  const int bid = blockIdx.x;
  const int bh = bid >> 5, c = bid & 31;
  const int b = bh >> 2, h = bh & 3;
  const int t0 = c * 64;
  const int tid = threadIdx.x;
  const int w = tid >> 6, l = tid & 63;
  const int ln = l & 15, lg = l >> 4;

  // ---- routing preamble: wave w handles rows w*16 .. w*16+15 ----
  {
    const float edt = expf(dt[h]);
    float waR[16], wbR[16];
#pragma unroll
    for (int i = 0; i < 16; ++i) {
      waR[i] = Wa[(l + 64 * i) * HH + h];
      wbR[i] = Wb[(l + 64 * i) * HH + h];
    }
#pragma unroll 1
    for (int j = 0; j < 16; ++j) {
      const int r = w * 16 + j;
      const size_t grow = (size_t)(b * TT + t0 + r);
      const float* hrow = hidden + grow * DD;
      float aa = 0.f, bb = 0.f;
#pragma unroll
      for (int i = 0; i < 16; ++i) {
        float hv = hrow[l + 64 * i];
        aa = fmaf(hv, waR[i], aa);
        bb = fmaf(hv, wbR[i], bb);
      }
      aa = wave_sum(aa);
      bb = wave_sum(bb);
      float sp = (aa > 20.f) ? aa : log1pf(expf(aa));
      float a_ = -sp * edt;
      float beta = 1.f / (1.f + expf(-bb));

      float4 rt4 = *(const float4*)(rproj + grow * DD + h * 256 + l * 4);
      float rv[4] = {rt4.x, rt4.y, rt4.z, rt4.w};
      int used = 0;
      int widx[4];
      float wsig[4], wg_[4], wkfac_[4];
#pragma unroll
      for (int it = 0; it < 4; ++it) {
        float bv = -3.4e38f;
        int bi = 0x7fffffff;
#pragma unroll
        for (int cc = 0; cc < 4; ++cc) {
          bool ok = !(used & (1 << cc));
          float v = rv[cc];
          if (ok && (v > bv)) {
            bv = v;
            bi = l * 4 + cc;
          }
        }
#pragma unroll
        for (int off = 32; off >= 1; off >>= 1) {
          float ov = __shfl_xor(bv, off);
          int oi = __shfl_xor(bi, off);
          if (ov > bv || (ov == bv && oi < bi)) {
            bv = ov;
            bi = oi;
          }
        }
        widx[it] = bi;
        wsig[it] = 1.f / (1.f + expf(-bv));
        if ((bi >> 2) == l) used |= 1 << (bi & 3);
      }
      float wsum = wsig[0] + wsig[1] + wsig[2] + wsig[3] + 1e-6f;
#pragma unroll
      for (int it = 0; it < 4; ++it) {
        float g = a_ * (wsig[it] / wsum);
        wg_[it] = g;
        wkfac_[it] = 1.f - expf(g);
      }

      // k-norm over this row (lane l holds slots 4l..4l+3)
      float4 kv4 = *(const float4*)(qkv + grow * 3072 + 1024 + h * 256 + l * 4);
      float kvv[4] = {kv4.x, kv4.y, kv4.z, kv4.w};
      float ssum = 0.f;
#pragma unroll
      for (int cc = 0; cc < 4; ++cc) {
        int slot = l * 4 + cc;
        float f = 0.f;
#pragma unroll
        for (int it = 0; it < 4; ++it)
          f = (slot == widx[it]) ? wkfac_[it] : f;
        float km = siluf(kvv[cc]) * f;
        ssum += km * km;
      }
      ssum = wave_sum(ssum);
      float kn = rsqrtf(ssum + 1e-6f);

      float4 qv4 = *(const float4*)(qkv + grow * 3072 + h * 256 + l * 4);
      float qs0 = siluf(qv4.x), qs1 = siluf(qv4.y), qs2 = siluf(qv4.z),
            qs3 = siluf(qv4.w);
      float qss = qs0 * qs0 + qs1 * qs1 + qs2 * qs2 + qs3 * qs3;
      qss = wave_sum(qss);
      float qn = rsqrtf(qss + 1e-6f) * 0.0625f;

      if (l == 0) {
        betaL[r] = beta;
        knL[r] = kn;
        qnL[r] = qn;
#pragma unroll
        for (int it = 0; it < 4; ++it) {
          widxL[r][it] = widx[it];
          wgL[r][it] = wg_[it];
          wkfacL[r][it] = wkfac_[it];
        }
        betaT[(size_t)bh * TT + t0 + r] = beta;
      }
    }
  }
  __syncthreads();

  // ---- stage 0: cumsum + bf16 staging (masks/norms applied inline) ----
  {
    float cacc = 0.f;
    const int slot = tid >> 3, byt = tid & 7;
#pragma unroll 4
    for (int i = 0; i < 64; ++i) {
      size_t ga = ((size_t)bh * TT + t0 + i) * 256 + tid;
      size_t pq = (size_t)(b * TT + t0 + i) * 3072 + h * 256 + tid;
      int w0 = widxL[i][0], w1 = widxL[i][1], w2 = widxL[i][2], w3 = widxL[i][3];
      float g = 0.f, f = 0.f;
      if (tid == w0) { g = wgL[i][0]; f = wkfacL[i][0]; }
      if (tid == w1) { g = wgL[i][1]; f = wkfacL[i][1]; }
      if (tid == w2) { g = wgL[i][2]; f = wkfacL[i][2]; }
      if (tid == w3) { g = wgL[i][3]; f = wkfacL[i][3]; }
      cacc += g;
      float e = expf(cacc);
      float ei = __builtin_amdgcn_rcpf(e);
      float qv = siluf(qkv[pq]) * qnL[i];
      float kv = siluf(qkv[pq + 1024]) * f * knL[i];
      unsigned short wb = f2bf(kv * e);
      unsigned short qb = f2bf(qv * e);
      unsigned short xb = f2bf(kv * ei);
      Wg[ga] = wb;
      Qg[ga] = qb;
      int sw = ((slot ^ (i & 7)) << 3) + byt;
      XB[i * 256 + sw] = xb;
      QW[i * 256 + sw] = qb;
      QW[(i + 64) * 256 + sw] = wb;
      if (i == 63) expcG[ga] = e;
    }
  }
  __syncthreads();

  f32x4 acc[2][4];
#pragma unroll
  for (int tr = 0; tr < 2; ++tr)
#pragma unroll
    for (int tc = 0; tc < 4; ++tc) acc[tr][tc] = (f32x4){0.f, 0.f, 0.f, 0.f};
  const int R0 = w * 32;
#pragma unroll
  for (int kt = 0; kt < 8; ++kt) {
    const int ks = kt * 4 + lg;
    const int ra0 = R0 + ln, ra1 = R0 + 16 + ln;
    bf16x8 a0 = *(const bf16x8*)&QW[ra0 * 256 + ((ks ^ (ra0 & 7)) << 3)];
    bf16x8 a1 = *(const bf16x8*)&QW[ra1 * 256 + ((ks ^ (ra1 & 7)) << 3)];
#pragma unroll
    for (int tc = 0; tc < 4; ++tc) {
      const int br = tc * 16 + ln;
      bf16x8 bf_ = *(const bf16x8*)&XB[br * 256 + ((ks ^ (br & 7)) << 3)];
      acc[0][tc] = __builtin_amdgcn_mfma_f32_16x16x32_bf16(a0, bf_, acc[0][tc], 0, 0, 0);
      acc[1][tc] = __builtin_amdgcn_mfma_f32_16x16x32_bf16(a1, bf_, acc[1][tc], 0, 0, 0);
    }
  }
  const size_t gb = (((size_t)bh * 32 + c) << 12);
  if (w < 2) {
#pragma unroll
    for (int tr = 0; tr < 2; ++tr)
#pragma unroll
      for (int tc = 0; tc < 4; ++tc)
#pragma unroll
        for (int r = 0; r < 4; ++r) {
          int i = R0 + tr * 16 + lg * 4 + r;
          int s = tc * 16 + ln;
          AB[gb + i * 64 + s] = (s <= i) ? f2bf(acc[tr][tc][r]) : (unsigned short)0;
        }
  } else {
#pragma unroll
    for (int tr = 0; tr < 2; ++tr)
#pragma unroll
      for (int tc = 0; tc < 4; ++tc)
#pragma unroll
        for (int r = 0; r < 4; ++r) {
          int i = R0 - 64 + tr * 16 + lg * 4 + r;
          Mb[i * 68 + tc * 16 + ln] = acc[tr][tc][r];
        }
  }
  __syncthreads();

  if (w == 0) {
    float tcol[64];
#pragma unroll
    for (int i = 0; i < 64; ++i) {
      float bi = betaL[i];
      float a_ = (l == i) ? 1.f : 0.f;
#pragma unroll
      for (int s = 0; s < i; ++s)
        a_ = fmaf(-bi * Mb[i * 68 + s], tcol[s], a_);
      tcol[i] = a_;
    }
#pragma unroll
    for (int s = 0; s < 64; ++s) Mb[s * 68 + l] = tcol[s];
  } else {
    const int kk1 = tid - 64;
#pragma unroll 1
    for (int pass = 0; pass < 2; ++pass) {
      if (pass == 1 && kk1 >= 64) break;
      const int k = (pass == 0) ? kk1 : (192 + kk1);
      unsigned short* dst = XTg + ((size_t)bh * 256 + k) * TT + t0;
      const int kslot = k >> 3, kb = k & 7;
#pragma unroll 1
      for (int jq = 0; jq < 8; ++jq) {
        unsigned short e[8];
#pragma unroll
        for (int j = 0; j < 8; ++j) {
          int t = jq * 8 + j;
          e[j] = XB[t * 256 + (((kslot ^ (t & 7)) << 3) + kb)];
        }
        uint4 o;
        o.x = ((unsigned)e[0]) | (((unsigned)e[1]) << 16);
        o.y = ((unsigned)e[2]) | (((unsigned)e[3]) << 16);
        o.z = ((unsigned)e[4]) | (((unsigned)e[5]) << 16);
        o.w = ((unsigned)e[6]) | (((unsigned)e[7]) << 16);
        *(uint4*)(dst + jq * 8) = o;
      }
    }
  }
  __syncthreads();
  {
    const int i = tid >> 2;
    const int sb = (tid & 3) * 16;
#pragma unroll
    for (int mq = 0; mq < 4; ++mq) {
      float v0 = Mb[i * 68 + sb + mq * 4 + 0];
      float v1 = Mb[i * 68 + sb + mq * 4 + 1];
      float v2 = Mb[i * 68 + sb + mq * 4 + 2];
      float v3 = Mb[i * 68 + sb + mq * 4 + 3];
      uint2 p;
      p.x = pack2(v0, v1);
      p.y = pack2(v2, v3);
      *(uint2*)(TinvB + gb + (size_t)i * 64 + sb + mq * 4) = p;
    }
  }
}

// ---------------- phase B: pipelined MFMA chunk scan (R12 structure) -------
__global__ __launch_bounds__(256) void chunk_scan_kernel(
    const unsigned short* __restrict__ Wg, const unsigned short* __restrict__ Qg,
    const unsigned short* __restrict__ XTg, const unsigned short* __restrict__ Tb,
    const unsigned short* __restrict__ Ab, const float* __restrict__ qkv,
    const float* __restrict__ expcG, const float* __restrict__ betaT,
    float* __restrict__ obuf) {
  __shared__ unsigned short ShL[16 * 256];  // [n][k], 16B-slot swizzle ^n
  __shared__ unsigned short SlL[16 * 256];
  __shared__ unsigned short R2bL[16 * 64];  // [n][t], slot swizzle ^(n&7)
  __shared__ unsigned short UbL[16 * 64];
  const int bid = blockIdx.x;
  const int bh = bid & 15, slice = bid >> 4;  // all slices of bh -> same XCD
  const int b = bh >> 2, h = bh & 3;
  const int tid = threadIdx.x;
  const int w = tid >> 6;
  const int l = tid & 63;
  const int ln = l & 15, lg = l >> 4;

  const unsigned short* Wbh = Wg + (size_t)bh * TT * 256;
  const unsigned short* Qbh = Qg + (size_t)bh * TT * 256;
  const unsigned short* XTbh = XTg + (size_t)bh * 256 * TT;
  const unsigned short* Tbh = Tb + (size_t)bh * 32 * 4096;
  const unsigned short* Abh = Ab + (size_t)bh * 32 * 4096;
  const float* betabh = betaT + (size_t)bh * TT;
  const float* ebh = expcG + (size_t)bh * TT * 256;

  f32x4 S0 = {0.f, 0.f, 0.f, 0.f}, S1 = S0, S2 = S0, S3 = S0;

  const int ru_off =
      ln * 64 + ((((w * 2) + (lg >> 1)) ^ (ln & 7)) << 3) + (lg & 1) * 4;

  bf16x8 wA[8], qA[8], wB[8], qB[8];
  float4 vA, bA, vB, bB;

#define LOADWQV(W_, Q_, V_, B_, c_)                                            \
  {                                                                            \
    const int t0_ = (c_) * 64;                                                 \
    _Pragma("unroll") for (int kt = 0; kt < 8; ++kt) {                         \
      const size_t arow =                                                      \
          (size_t)(t0_ + w * 16 + ln) * 256 + kt * 32 + lg * 8;                \
      W_[kt] = *(const bf16x8*)(Wbh + arow);                                   \
      Q_[kt] = *(const bf16x8*)(Qbh + arow);                                   \
    }                                                                          \
    const size_t vrow = (size_t)(b * TT + t0_ + w * 16 + lg * 4) * 3072 +      \
                        2048 + h * 256 + slice * 16 + ln;                      \
    V_.x = siluf(qkv[vrow]);                                                   \
    V_.y = siluf(qkv[vrow + 3072]);                                            \
    V_.z = siluf(qkv[vrow + 2 * 3072]);                                        \
    V_.w = siluf(qkv[vrow + 3 * 3072]);                                        \
    B_ = *(const float4*)(betabh + t0_ + w * 16 + lg * 4);                     \
  }

#define SSTORE(S_, E_, mt_)                                                    \
  {                                                                            \
    S_[0] *= E_.x;                                                             \
    S_[1] *= E_.y;                                                             \
    S_[2] *= E_.z;                                                             \
    S_[3] *= E_.w;                                                             \
    ushort4 hp, lp;                                                            \
    hp.x = f2bf(S_[0]); lp.x = f2bf(S_[0] - bf2f(hp.x));                       \
    hp.y = f2bf(S_[1]); lp.y = f2bf(S_[1] - bf2f(hp.y));                       \
    hp.z = f2bf(S_[2]); lp.z = f2bf(S_[2] - bf2f(hp.z));                       \
    hp.w = f2bf(S_[3]); lp.w = f2bf(S_[3] - bf2f(hp.w));                       \
    const int so_ = ln * 256 +                                                 \
                    ((((w * 8) + (mt_)*2 + (lg >> 1)) ^ ln) << 3) +            \
                    (lg & 1) * 4;                                              \
    *(ushort4*)(&ShL[so_]) = hp;                                               \
    *(ushort4*)(&SlL[so_]) = lp;                                               \
  }

#define CHUNK(Wc, Qc, Vc, Bc, Wn, Qn, Vn, Bn, c_)                              \
  {                                                                            \
    const int c = (c_);                                                        \
    const size_t tb_base = (size_t)c * 4096 + (w * 16 + ln) * 64 + lg * 8;     \
    bf16x8 tf0 = *(const bf16x8*)(Tbh + tb_base);                              \
    bf16x8 tf1 = *(const bf16x8*)(Tbh + tb_base + 32);                         \
    bf16x8 af0 = *(const bf16x8*)(Abh + tb_base);                              \
    bf16x8 af1 = *(const bf16x8*)(Abh + tb_base + 32);                         \
    const size_t xb = (size_t)(w * 64 + ln) * TT + c * 64 + lg * 8;            \
    bf16x8 xf0a = *(const bf16x8*)(XTbh + xb);                                 \
    bf16x8 xf0b = *(const bf16x8*)(XTbh + xb + 32);                            \
    bf16x8 xf1a = *(const bf16x8*)(XTbh + xb + 16 * TT);                       \
    bf16x8 xf1b = *(const bf16x8*)(XTbh + xb + 16 * TT + 32);                  \
    bf16x8 xf2a = *(const bf16x8*)(XTbh + xb + 32 * TT);                       \
    bf16x8 xf2b = *(const bf16x8*)(XTbh + xb + 32 * TT + 32);                  \
    bf16x8 xf3a = *(const bf16x8*)(XTbh + xb + 48 * TT);                       \
    bf16x8 xf3b = *(const bf16x8*)(XTbh + xb + 48 * TT + 32);                  \
    const float* ebase = ebh + (size_t)(c * 64 + 63) * 256 + w * 64 + lg * 4;  \
    float4 eL0 = *(const float4*)(ebase);                                      \
    float4 eL1 = *(const float4*)(ebase + 16);                                 \
    float4 eL2 = *(const float4*)(ebase + 32);                                 \
    float4 eL3 = *(const float4*)(ebase + 48);                                 \
    f32x4 rhs = {0.f, 0.f, 0.f, 0.f}, oq = {0.f, 0.f, 0.f, 0.f};               \
    if (c > 0) {                                                               \
      _Pragma("unroll") for (int kt = 0; kt < 8; ++kt) {                       \
        const int sro = ln * 256 + (((kt * 4 + lg) ^ ln) << 3);                \
        bf16x8 sh = *(const bf16x8*)(&ShL[sro]);                               \
        bf16x8 sl = *(const bf16x8*)(&SlL[sro]);                               \
        rhs = __builtin_amdgcn_mfma_f32_16x16x32_bf16(Wc[kt], sh, rhs, 0, 0, 0); \
        rhs = __builtin_amdgcn_mfma_f32_16x16x32_bf16(Wc[kt], sl, rhs, 0, 0, 0); \
        oq = __builtin_amdgcn_mfma_f32_16x16x32_bf16(Qc[kt], sh, oq, 0, 0, 0); \
        oq = __builtin_amdgcn_mfma_f32_16x16x32_bf16(Qc[kt], sl, oq, 0, 0, 0); \
      }                                                                        \
    }                                                                          \
    if (c + 1 < 32) LOADWQV(Wn, Qn, Vn, Bn, c + 1);                            \
    {                                                                          \
      ushort4 r2p;                                                             \
      r2p.x = f2bf(Bc.x * (Vc.x - rhs[0]));                                    \
      r2p.y = f2bf(Bc.y * (Vc.y - rhs[1]));                                    \
      r2p.z = f2bf(Bc.z * (Vc.z - rhs[2]));                                    \
      r2p.w = f2bf(Bc.w * (Vc.w - rhs[3]));                                    \
      *(ushort4*)(&R2bL[ru_off]) = r2p;                                        \
    }                                                                          \
    LBAR();                                                                    \
    {                                                                          \
      bf16x8 rf0 = *(const bf16x8*)(&R2bL[ln * 64 + (((0 + lg) ^ (ln & 7)) << 3)]); \
      bf16x8 rf1 = *(const bf16x8*)(&R2bL[ln * 64 + (((4 + lg) ^ (ln & 7)) << 3)]); \
      f32x4 u = {0.f, 0.f, 0.f, 0.f};                                          \
      u = __builtin_amdgcn_mfma_f32_16x16x32_bf16(tf0, rf0, u, 0, 0, 0);       \
      u = __builtin_amdgcn_mfma_f32_16x16x32_bf16(tf1, rf1, u, 0, 0, 0);       \
      ushort4 up;                                                              \
      up.x = f2bf(u[0]);                                                       \
      up.y = f2bf(u[1]);                                                       \
      up.z = f2bf(u[2]);                                                       \
      up.w = f2bf(u[3]);                                                       \
      *(ushort4*)(&UbL[ru_off]) = up;                                          \
    }                                                                          \
    LBAR();                                                                    \
    bf16x8 uf0 = *(const bf16x8*)(&UbL[ln * 64 + (((0 + lg) ^ (ln & 7)) << 3)]); \
    bf16x8 uf1 = *(const bf16x8*)(&UbL[ln * 64 + (((4 + lg) ^ (ln & 7)) << 3)]); \
    {                                                                          \
      f32x4 o = oq;                                                            \
      o = __builtin_amdgcn_mfma_f32_16x16x32_bf16(af0, uf0, o, 0, 0, 0);       \
      o = __builtin_amdgcn_mfma_f32_16x16x32_bf16(af1, uf1, o, 0, 0, 0);       \
      const size_t orow =                                                      \
          ((size_t)(b * TT + c * 64 + w * 16 + lg * 4) * HH + h) * 256 +       \
          slice * 16 + ln;                                                     \
      obuf[orow] = o[0];                                                       \
      obuf[orow + HH * 256] = o[1];                                            \
      obuf[orow + 2 * HH * 256] = o[2];                                        \
      obuf[orow + 3 * HH * 256] = o[3];                                        \
    }                                                                          \
    S0 = __builtin_amdgcn_mfma_f32_16x16x32_bf16(xf0a, uf0, S0, 0, 0, 0);      \
    S0 = __builtin_amdgcn_mfma_f32_16x16x32_bf16(xf0b, uf1, S0, 0, 0, 0);      \
    S1 = __builtin_amdgcn_mfma_f32_16x16x32_bf16(xf1a, uf0, S1, 0, 0, 0);      \
    S1 = __builtin_amdgcn_mfma_f32_16x16x32_bf16(xf1b, uf1, S1, 0, 0, 0);      \
    S2 = __builtin_amdgcn_mfma_f32_16x16x32_bf16(xf2a, uf0, S2, 0, 0, 0);      \
    S2 = __builtin_amdgcn_mfma_f32_16x16x32_bf16(xf2b, uf1, S2, 0, 0, 0);      \
    S3 = __builtin_amdgcn_mfma_f32_16x16x32_bf16(xf3a, uf0, S3, 0, 0, 0);      \
    S3 = __builtin_amdgcn_mfma_f32_16x16x32_bf16(xf3b, uf1, S3, 0, 0, 0);      \
    SSTORE(S0, eL0, 0);                                                        \
    SSTORE(S1, eL1, 1);                                                        \
    SSTORE(S2, eL2, 2);                                                        \
    SSTORE(S3, eL3, 3);                                                        \
    LBAR();                                                                    \
  }

  LOADWQV(wA, qA, vA, bA, 0);
  for (int cc = 0; cc < 32; cc += 2) {
    CHUNK(wA, qA, vA, bA, wB, qB, vB, bB, cc);
    CHUNK(wB, qB, vB, bB, wA, qA, vA, bA, cc + 1);
  }
#undef CHUNK
#undef SSTORE
#undef LOADWQV
}

// ---------------- per-head RMSNorm, fused bf16 cast ----------------
__global__ __launch_bounds__(256) void rmsnorm_bf16_kernel(
    const float* __restrict__ o, const float* __restrict__ w,
    unsigned short* __restrict__ out) {
  const int row = blockIdx.x;
  const int l = threadIdx.x & 63;
  const size_t base = (size_t)row * DD + (threadIdx.x >> 6) * 256 + l * 4;
  float4 x = *(const float4*)(o + base);
  float ss = x.x * x.x + x.y * x.y + x.z * x.z + x.w * x.w;
  ss = wave_sum(ss);
  float sc = rsqrtf(ss * (1.f / 256.f) + 1e-5f);
  float4 wv = *(const float4*)(w + l * 4);
  ushort4 o4;
  o4.x = f2bf(x.x * sc * wv.x);
  o4.y = f2bf(x.y * sc * wv.y);
  o4.z = f2bf(x.z * sc * wv.z);
  o4.w = f2bf(x.w * sc * wv.w);
  *(ushort4*)(out + base) = o4;
}

extern "C" void kernel_launch(void* const* d_in, const int* in_sizes, int n_in,
                              void* d_out, int out_size, void* d_ws,
                              size_t ws_size, hipStream_t stream) {
  const float* hidden = (const float*)d_in[0];
  const float* Wq = (const float*)d_in[1];
  const float* Wk = (const float*)d_in[2];
  const float* Wv = (const float*)d_in[3];
  const float* Wa = (const float*)d_in[4];
  const float* Wr = (const float*)d_in[5];
  const float* Wb = (const float*)d_in[6];
  const float* dt = (const float*)d_in[7];
  const float* norm_w = (const float*)d_in[8];
  const float* Wo = (const float*)d_in[9];
  float* out = (float*)d_out;

  const size_t NP = (size_t)BB * TT * DD;  // 8388608
  float* ws = (float*)d_ws;
  float* qkv = ws;            // [8192][3072] (q|k|v raw projections)
  float* gbuf = ws + 3 * NP;  // expc: only row63-per-chunk written/read
  unsigned short* hbf = (unsigned short*)(ws + 4 * NP);
  unsigned short* wT = (unsigned short*)(ws + 4 * NP + NP / 2);
  unsigned short* WT0 = wT;                // Wq^T (q|k|v|o contiguous)
  unsigned short* WT3 = wT + 3 * 1048576;  // Wo^T
  unsigned short* WT4 = wT + 4 * 1048576;  // Wr^T hi
  unsigned short* WT5 = wT + 5 * 1048576;  // Wr^T lo
  float* betaT = ws + 4 * NP + NP / 2 + 3 * 1024 * 1024;
  float* after_beta = betaT + 16 * TT;
  unsigned short* Qg = (unsigned short*)after_beta;
  unsigned short* XTg = Qg + NP;
  unsigned short* Ab = XTg + NP;
  unsigned short* Wgb = hbf;
  unsigned short* Tbb = WT4;
  unsigned short* hlo = (unsigned short*)qkv;
  float* rproj = out;

  dim3 bt(256);
  cast2_bf16_kernel<<<8192, 256, 0, stream>>>(hidden, hbf, hlo);
  tcast_all_kernel<<<5120, dim3(32, 8), 0, stream>>>(Wq, Wk, Wv, Wo, Wr, WT0,
                                                     WT4, WT5);

  gemm_bt3<<<512, bt, 0, stream>>>(hbf, hlo, WT4, WT5, rproj, 8192, 1024, 1024);
  gemm_bt<<<1536, bt, 0, stream>>>(hbf, WT0, qkv, 8192, 3072, 1024);

  phaseA_kernel<<<512, 256, 0, stream>>>(hidden, Wa, Wb, dt, rproj, qkv, gbuf,
                                         betaT, Tbb, Ab, Wgb, Qg, XTg);
  chunk_scan_kernel<<<256, 256, 0, stream>>>(Wgb, Qg, XTg, Tbb, Ab, qkv, gbuf,
                                             betaT, out);
  rmsnorm_bf16_kernel<<<8192, 256, 0, stream>>>(out, norm_w, hbf);
  gemm_bt<<<512, bt, 0, stream>>>(hbf, WT3, out, 8192, 1024, 1024);
}

// Round 19
// 432.054 us; speedup vs baseline: 1.2694x; 1.2694x over previous
//
#include <hip/hip_runtime.h>
#include <hip/hip_bf16.h>

#define TT 2048
#define BB 4
#define HH 4
#define DD 1024

using bf16x8 = __attribute__((ext_vector_type(8))) short;
using f32x4  = __attribute__((ext_vector_type(4))) float;

__device__ __forceinline__ float wave_sum(float x) {
#pragma unroll
  for (int off = 32; off >= 1; off >>= 1) x += __shfl_xor(x, off);
  return x;
}

__device__ __forceinline__ float siluf(float x) {
  return x / (1.f + expf(-x));
}

__device__ __forceinline__ unsigned short f2bf(float f) {
  unsigned u = __float_as_uint(f);
  u = (u + 0x7fffu + ((u >> 16) & 1u)) >> 16;
  return (unsigned short)u;
}
__device__ __forceinline__ float bf2f(unsigned short b) {
  return __uint_as_float(((unsigned)b) << 16);
}
__device__ __forceinline__ unsigned pack2(float a, float b) {
  return ((unsigned)f2bf(a)) | (((unsigned)f2bf(b)) << 16);
}

// async global->LDS, 16B per lane; dest = lds base + lane*16 (linear)
__device__ __forceinline__ void gload_lds16(const void* g, void* l) {
  __builtin_amdgcn_global_load_lds(
      (const __attribute__((address_space(1))) unsigned int*)g,
      (__attribute__((address_space(3))) unsigned int*)l, 16, 0, 0);
}

// LDS-only barrier: drain ds ops, raw barrier, pin scheduler.
#define LBAR()                                              \
  do {                                                      \
    asm volatile("s_waitcnt lgkmcnt(0)" ::: "memory");      \
    __builtin_amdgcn_s_barrier();                           \
    __builtin_amdgcn_sched_barrier(0);                      \
  } while (0)

// ---------------- bf16 MFMA GEMM: C[M,N] = A[M,K] @ B[K,N], Bt is [N][K] ----
__global__ __launch_bounds__(256) void gemm_bt(const unsigned short* __restrict__ A,
                                               const unsigned short* __restrict__ Bt,
                                               float* __restrict__ C,
                                               int M, int N, int K) {
  __shared__ unsigned short As[128 * 64];
  __shared__ unsigned short Bs[128 * 64];
  const int tid = threadIdx.x;
  const int l = tid & 63;
  const int w = tid >> 6;
  const int wm = w >> 1, wn = w & 1;
  const int bid = blockIdx.x;
  const int nt = N >> 7;
  const int swz = (bid & 7) * ((int)gridDim.x >> 3) + (bid >> 3);
  const int m0 = (swz / nt) * 128, n0 = (swz % nt) * 128;

  f32x4 acc[4][4];
#pragma unroll
  for (int i = 0; i < 4; ++i)
#pragma unroll
    for (int j = 0; j < 4; ++j) acc[i][j] = (f32x4){0.f, 0.f, 0.f, 0.f};

  size_t asrc[4], bsrc[4];
  int ldst[4];
#pragma unroll
  for (int it = 0; it < 4; ++it) {
    int chunk = (it * 4 + w) * 64 + l;
    int row = chunk >> 3, s = chunk & 7;
    size_t soff = (size_t)row * K + ((s ^ (row & 7)) << 3);
    asrc[it] = (size_t)m0 * K + soff;
    bsrc[it] = (size_t)n0 * K + soff;
    ldst[it] = chunk * 8;
  }
  int ra_off[2][4], rb_off[2][4];
#pragma unroll
  for (int kh = 0; kh < 2; ++kh)
#pragma unroll
    for (int f = 0; f < 4; ++f) {
      int rowA = wm * 64 + f * 16 + (l & 15);
      ra_off[kh][f] = rowA * 128 + (((kh * 4 + (l >> 4)) ^ (rowA & 7)) << 4);
      int rowB = wn * 64 + f * 16 + (l & 15);
      rb_off[kh][f] = rowB * 128 + (((kh * 4 + (l >> 4)) ^ (rowB & 7)) << 4);
    }

  for (int k0 = 0; k0 < K; k0 += 64) {
    __syncthreads();
#pragma unroll
    for (int it = 0; it < 4; ++it) {
      gload_lds16(A + asrc[it] + k0, As + ldst[it] - l * 8);
      gload_lds16(Bt + bsrc[it] + k0, Bs + ldst[it] - l * 8);
    }
    __syncthreads();
#pragma unroll
    for (int kh = 0; kh < 2; ++kh) {
      bf16x8 af[4], bfv[4];
#pragma unroll
      for (int f = 0; f < 4; ++f) {
        af[f] = *(const bf16x8*)((const char*)As + ra_off[kh][f]);
        bfv[f] = *(const bf16x8*)((const char*)Bs + rb_off[kh][f]);
      }
#pragma unroll
      for (int i = 0; i < 4; ++i)
#pragma unroll
        for (int j = 0; j < 4; ++j)
          acc[i][j] = __builtin_amdgcn_mfma_f32_16x16x32_bf16(af[i], bfv[j],
                                                              acc[i][j], 0, 0, 0);
    }
  }
  const int cn = n0 + wn * 64 + (l & 15);
  const int rbase = m0 + wm * 64 + ((l >> 4) << 2);
#pragma unroll
  for (int i = 0; i < 4; ++i)
#pragma unroll
    for (int j = 0; j < 4; ++j)
#pragma unroll
      for (int r = 0; r < 4; ++r)
        C[(size_t)(rbase + i * 16 + r) * N + cn + j * 16] = acc[i][j][r];
}

// ---- fused projections: bid<1536 -> qkv (bf16 GEMM, N=3072); else ->
// rproj split-bf16 3-term GEMM (N=1024). 64KB dynamic LDS shared by both.
// NOTE: hlo must NOT alias qkv (paths run concurrently) -- caller aliases
// hlo to gbuf (written only later by routing).
__global__ __launch_bounds__(256) void proj_fused_kernel(
    const unsigned short* __restrict__ Ah, const unsigned short* __restrict__ Al,
    const unsigned short* __restrict__ Wqkv, const unsigned short* __restrict__ Brh,
    const unsigned short* __restrict__ Brl, float* __restrict__ qkv,
    float* __restrict__ rproj) {
  extern __shared__ unsigned short smem[];
  const int tid = threadIdx.x;
  const int l = tid & 63;
  const int w = tid >> 6;
  const int wm = w >> 1, wn = w & 1;
  const int K = 1024;

  if (blockIdx.x < 1536) {
    // ---------- qkv path ----------
    unsigned short* As = smem;
    unsigned short* Bs = smem + 128 * 64;
    const int bid = blockIdx.x;
    const int nt = 24;  // 3072/128
    const int swz = (bid & 7) * (1536 >> 3) + (bid >> 3);
    const int m0 = (swz / nt) * 128, n0 = (swz % nt) * 128;

    f32x4 acc[4][4];
#pragma unroll
    for (int i = 0; i < 4; ++i)
#pragma unroll
      for (int j = 0; j < 4; ++j) acc[i][j] = (f32x4){0.f, 0.f, 0.f, 0.f};

    size_t asrc[4], bsrc[4];
    int ldst[4];
#pragma unroll
    for (int it = 0; it < 4; ++it) {
      int chunk = (it * 4 + w) * 64 + l;
      int row = chunk >> 3, s = chunk & 7;
      size_t soff = (size_t)row * K + ((s ^ (row & 7)) << 3);
      asrc[it] = (size_t)m0 * K + soff;
      bsrc[it] = (size_t)n0 * K + soff;
      ldst[it] = chunk * 8;
    }
    int ra_off[2][4], rb_off[2][4];
#pragma unroll
    for (int kh = 0; kh < 2; ++kh)
#pragma unroll
      for (int f = 0; f < 4; ++f) {
        int rowA = wm * 64 + f * 16 + (l & 15);
        ra_off[kh][f] = rowA * 128 + (((kh * 4 + (l >> 4)) ^ (rowA & 7)) << 4);
        int rowB = wn * 64 + f * 16 + (l & 15);
        rb_off[kh][f] = rowB * 128 + (((kh * 4 + (l >> 4)) ^ (rowB & 7)) << 4);
      }

    for (int k0 = 0; k0 < K; k0 += 64) {
      __syncthreads();
#pragma unroll
      for (int it = 0; it < 4; ++it) {
        gload_lds16(Ah + asrc[it] + k0, As + ldst[it] - l * 8);
        gload_lds16(Wqkv + bsrc[it] + k0, Bs + ldst[it] - l * 8);
      }
      __syncthreads();
#pragma unroll
      for (int kh = 0; kh < 2; ++kh) {
        bf16x8 af[4], bfv[4];
#pragma unroll
        for (int f = 0; f < 4; ++f) {
          af[f] = *(const bf16x8*)((const char*)As + ra_off[kh][f]);
          bfv[f] = *(const bf16x8*)((const char*)Bs + rb_off[kh][f]);
        }
#pragma unroll
        for (int i = 0; i < 4; ++i)
#pragma unroll
          for (int j = 0; j < 4; ++j)
            acc[i][j] = __builtin_amdgcn_mfma_f32_16x16x32_bf16(af[i], bfv[j],
                                                                acc[i][j], 0, 0, 0);
      }
    }
    const int cn = n0 + wn * 64 + (l & 15);
    const int rbase = m0 + wm * 64 + ((l >> 4) << 2);
#pragma unroll
    for (int i = 0; i < 4; ++i)
#pragma unroll
      for (int j = 0; j < 4; ++j)
#pragma unroll
        for (int r = 0; r < 4; ++r)
          qkv[(size_t)(rbase + i * 16 + r) * 3072 + cn + j * 16] = acc[i][j][r];
  } else {
    // ---------- rproj split-bf16 3-term path ----------
    unsigned short* Ash = smem;
    unsigned short* Asl = smem + 128 * 64;
    unsigned short* Bsh = smem + 2 * 128 * 64;
    unsigned short* Bsl = smem + 3 * 128 * 64;
    const int bid = blockIdx.x - 1536;
    const int nt = 8;  // 1024/128
    const int swz = (bid & 7) * (512 >> 3) + (bid >> 3);
    const int m0 = (swz / nt) * 128, n0 = (swz % nt) * 128;

    f32x4 acc[4][4];
#pragma unroll
    for (int i = 0; i < 4; ++i)
#pragma unroll
      for (int j = 0; j < 4; ++j) acc[i][j] = (f32x4){0.f, 0.f, 0.f, 0.f};

    size_t asrc[4], bsrc[4];
    int ldst[4];
#pragma unroll
    for (int it = 0; it < 4; ++it) {
      int chunk = (it * 4 + w) * 64 + l;
      int row = chunk >> 3, s = chunk & 7;
      size_t soff = (size_t)row * K + ((s ^ (row & 7)) << 3);
      asrc[it] = (size_t)m0 * K + soff;
      bsrc[it] = (size_t)n0 * K + soff;
      ldst[it] = chunk * 8;
    }
    int ra_off[2][4], rb_off[2][4];
#pragma unroll
    for (int kh = 0; kh < 2; ++kh)
#pragma unroll
      for (int f = 0; f < 4; ++f) {
        int rowA = wm * 64 + f * 16 + (l & 15);
        ra_off[kh][f] = rowA * 128 + (((kh * 4 + (l >> 4)) ^ (rowA & 7)) << 4);
        int rowB = wn * 64 + f * 16 + (l & 15);
        rb_off[kh][f] = rowB * 128 + (((kh * 4 + (l >> 4)) ^ (rowB & 7)) << 4);
      }

    for (int k0 = 0; k0 < K; k0 += 64) {
      __syncthreads();
#pragma unroll
      for (int it = 0; it < 4; ++it) {
        gload_lds16(Ah + asrc[it] + k0, Ash + ldst[it] - l * 8);
        gload_lds16(Al + asrc[it] + k0, Asl + ldst[it] - l * 8);
        gload_lds16(Brh + bsrc[it] + k0, Bsh + ldst[it] - l * 8);
        gload_lds16(Brl + bsrc[it] + k0, Bsl + ldst[it] - l * 8);
      }
      __syncthreads();
#pragma unroll
      for (int kh = 0; kh < 2; ++kh) {
        bf16x8 afh[4], bfh[4], tmp[4];
#pragma unroll
        for (int f = 0; f < 4; ++f) {
          afh[f] = *(const bf16x8*)((const char*)Ash + ra_off[kh][f]);
          bfh[f] = *(const bf16x8*)((const char*)Bsh + rb_off[kh][f]);
        }
#pragma unroll
        for (int i = 0; i < 4; ++i)
#pragma unroll
          for (int j = 0; j < 4; ++j)
            acc[i][j] = __builtin_amdgcn_mfma_f32_16x16x32_bf16(afh[i], bfh[j],
                                                                acc[i][j], 0, 0, 0);
#pragma unroll
        for (int f = 0; f < 4; ++f)
          tmp[f] = *(const bf16x8*)((const char*)Asl + ra_off[kh][f]);
#pragma unroll
        for (int i = 0; i < 4; ++i)
#pragma unroll
          for (int j = 0; j < 4; ++j)
            acc[i][j] = __builtin_amdgcn_mfma_f32_16x16x32_bf16(tmp[i], bfh[j],
                                                                acc[i][j], 0, 0, 0);
#pragma unroll
        for (int f = 0; f < 4; ++f)
          tmp[f] = *(const bf16x8*)((const char*)Bsl + rb_off[kh][f]);
#pragma unroll
        for (int i = 0; i < 4; ++i)
#pragma unroll
          for (int j = 0; j < 4; ++j)
            acc[i][j] = __builtin_amdgcn_mfma_f32_16x16x32_bf16(afh[i], tmp[j],
                                                                acc[i][j], 0, 0, 0);
      }
    }
    const int cn = n0 + wn * 64 + (l & 15);
    const int rbase = m0 + wm * 64 + ((l >> 4) << 2);
#pragma unroll
    for (int i = 0; i < 4; ++i)
#pragma unroll
      for (int j = 0; j < 4; ++j)
#pragma unroll
        for (int r = 0; r < 4; ++r)
          rproj[(size_t)(rbase + i * 16 + r) * 1024 + cn + j * 16] = acc[i][j][r];
  }
}

// ---------------- casts ----------------
__global__ __launch_bounds__(256) void cast2_bf16_kernel(const float* __restrict__ in,
                                                         unsigned short* __restrict__ hi,
                                                         unsigned short* __restrict__ lo) {
  const size_t i = ((size_t)blockIdx.x * 256 + threadIdx.x) * 4;
  float4 x = *(const float4*)(in + i);
  ushort4 h4, l4;
  h4.x = f2bf(x.x); l4.x = f2bf(x.x - bf2f(h4.x));
  h4.y = f2bf(x.y); l4.y = f2bf(x.y - bf2f(h4.y));
  h4.z = f2bf(x.z); l4.z = f2bf(x.z - bf2f(h4.z));
  h4.w = f2bf(x.w); l4.w = f2bf(x.w - bf2f(h4.w));
  *(ushort4*)(hi + i) = h4;
  *(ushort4*)(lo + i) = l4;
}

// fused weight transpose+cast: which=0..3 -> Wq/Wk/Wv/Wo; which=4 -> Wr hi/lo.
__global__ __launch_bounds__(256) void tcast_all_kernel(
    const float* __restrict__ Wq, const float* __restrict__ Wk,
    const float* __restrict__ Wv, const float* __restrict__ Wo,
    const float* __restrict__ Wr, unsigned short* __restrict__ WT0,
    unsigned short* __restrict__ WTrH, unsigned short* __restrict__ WTrL) {
  __shared__ float tile[32][33];
  const int which = blockIdx.x >> 10;
  const int bid = blockIdx.x & 1023;
  const int bx = bid & 31, by = bid >> 5;
  const float* W = (which == 0) ? Wq
                   : (which == 1) ? Wk
                   : (which == 2) ? Wv
                   : (which == 3) ? Wo
                                  : Wr;
  const int tx = threadIdx.x, ty = threadIdx.y;
  const int c0 = bx * 32, r0 = by * 32;
#pragma unroll
  for (int i = 0; i < 4; ++i)
    tile[ty + 8 * i][tx] = W[(size_t)(r0 + ty + 8 * i) * 1024 + c0 + tx];
  __syncthreads();
  if (which < 4) {
    unsigned short* WT = WT0 + (size_t)which * 1048576;
#pragma unroll
    for (int i = 0; i < 4; ++i)
      WT[(size_t)(c0 + ty + 8 * i) * 1024 + r0 + tx] = f2bf(tile[tx][ty + 8 * i]);
  } else {
#pragma unroll
    for (int i = 0; i < 4; ++i) {
      float x = tile[tx][ty + 8 * i];
      unsigned short h = f2bf(x);
      WTrH[(size_t)(c0 + ty + 8 * i) * 1024 + r0 + tx] = h;
      WTrL[(size_t)(c0 + ty + 8 * i) * 1024 + r0 + tx] = f2bf(x - bf2f(h));
    }
  }
}

// ---------------- routing: qkv is [M][3072] (q|k|v per row); v untouched ----
__global__ __launch_bounds__(256) void routing_kernel(
    const float* __restrict__ hidden, const float* __restrict__ Wa,
    const float* __restrict__ Wb, const float* __restrict__ dt,
    const float* __restrict__ rproj, float* __restrict__ qkv,
    float* __restrict__ gbuf, float* __restrict__ betaT) {
  const int row = blockIdx.x;  // b*T + t
  const int b = row >> 11;
  const int t = row & (TT - 1);
  const int h = threadIdx.x >> 6;
  const int l = threadIdx.x & 63;
  const size_t base_q = (size_t)row * 3072 + h * 256;
  const size_t base_k = base_q + 1024;
  const size_t base_r = (size_t)row * DD + h * 256;

  const float* hrow = hidden + (size_t)row * DD;
  float aa = 0.f, bb = 0.f;
#pragma unroll
  for (int i = 0; i < 16; ++i) {
    float hv = hrow[l + 64 * i];
    aa = fmaf(hv, Wa[(l + 64 * i) * HH + h], aa);
    bb = fmaf(hv, Wb[(l + 64 * i) * HH + h], bb);
  }
  aa = wave_sum(aa);
  bb = wave_sum(bb);
  float sp = (aa > 20.f) ? aa : log1pf(expf(aa));
  float a_ = -sp * expf(dt[h]);
  float beta = 1.f / (1.f + expf(-bb));
  const int bh = b * HH + h;
  if (l == 0) betaT[(size_t)bh * TT + t] = beta;

  float4 rt4 = *(const float4*)(rproj + base_r + l * 4);
  float rv[4] = {rt4.x, rt4.y, rt4.z, rt4.w};
  int used = 0;
  int widx[4];
  float wsig[4], wg[4], wkfac[4];
#pragma unroll
  for (int it = 0; it < 4; ++it) {
    float bv = -3.4e38f;
    int bi = 0x7fffffff;
#pragma unroll
    for (int c = 0; c < 4; ++c) {
      bool ok = !(used & (1 << c));
      float v = rv[c];
      if (ok && (v > bv)) {
        bv = v;
        bi = l * 4 + c;
      }
    }
#pragma unroll
    for (int off = 32; off >= 1; off >>= 1) {
      float ov = __shfl_xor(bv, off);
      int oi = __shfl_xor(bi, off);
      if (ov > bv || (ov == bv && oi < bi)) {
        bv = ov;
        bi = oi;
      }
    }
    widx[it] = bi;
    wsig[it] = 1.f / (1.f + expf(-bv));
    if ((bi >> 2) == l) used |= 1 << (bi & 3);
  }
  float wsum = wsig[0] + wsig[1] + wsig[2] + wsig[3] + 1e-6f;
#pragma unroll
  for (int it = 0; it < 4; ++it) {
    float g = a_ * (wsig[it] / wsum);
    wg[it] = g;
    wkfac[it] = 1.f - expf(g);
  }

  float4 kv4 = *(const float4*)(qkv + base_k + l * 4);
  float kvv[4] = {kv4.x, kv4.y, kv4.z, kv4.w};
  float kmask[4], ddv[4];
#pragma unroll
  for (int c = 0; c < 4; ++c) {
    int slot = l * 4 + c;
    float f = 0.f, d = 0.f;
#pragma unroll
    for (int it = 0; it < 4; ++it) {
      bool hit = (slot == widx[it]);
      f = hit ? wkfac[it] : f;
      d = hit ? wg[it] : d;
    }
    kmask[c] = siluf(kvv[c]) * f;
    ddv[c] = d;
  }
  float ss = kmask[0] * kmask[0] + kmask[1] * kmask[1] + kmask[2] * kmask[2] +
             kmask[3] * kmask[3];
  ss = wave_sum(ss);
  float kn = rsqrtf(ss + 1e-6f);
  *(float4*)(qkv + base_k + l * 4) =
      make_float4(kmask[0] * kn, kmask[1] * kn, kmask[2] * kn, kmask[3] * kn);
  *(float4*)(gbuf + ((size_t)bh * TT + t) * 256 + l * 4) =
      make_float4(ddv[0], ddv[1], ddv[2], ddv[3]);

  float4 qv4 = *(const float4*)(qkv + base_q + l * 4);
  float qs[4] = {siluf(qv4.x), siluf(qv4.y), siluf(qv4.z), siluf(qv4.w)};
  float qss = qs[0] * qs[0] + qs[1] * qs[1] + qs[2] * qs[2] + qs[3] * qs[3];
  qss = wave_sum(qss);
  float qn = rsqrtf(qss + 1e-6f) * 0.0625f;
  *(float4*)(qkv + base_q + l * 4) =
      make_float4(qs[0] * qn, qs[1] * qn, qs[2] * qn, qs[3] * qn);
  // v: silu applied at consumption in chunk_scan (identical fp32 math)
}

// ---------------- phase A (MFMA): cumsum; P=[Qw;W]@X^T via mfma; Tinv; bf16 out
__global__ __launch_bounds__(256) void phaseA_kernel(
    const float* __restrict__ qkv,
    float* __restrict__ expcG,
    const float* __restrict__ betaT, unsigned short* __restrict__ TinvB,
    unsigned short* __restrict__ AB, unsigned short* __restrict__ Wg,
    unsigned short* __restrict__ Qg, unsigned short* __restrict__ XTg) {
  __shared__ unsigned short XB[64 * 256];
  __shared__ unsigned short QW[128 * 256];
  __shared__ float Mb[64 * 68];
  const int bid = blockIdx.x;
  const int bh = bid >> 5, c = bid & 31;
  const int b = bh >> 2, h = bh & 3;
  const int t0 = c * 64;
  const int tid = threadIdx.x;
  const int w = tid >> 6, l = tid & 63;
  const int ln = l & 15, lg = l >> 4;

  {
    float cacc = 0.f;
    const int slot = tid >> 3, byt = tid & 7;
#pragma unroll 4
    for (int i = 0; i < 64; ++i) {
      size_t ga = ((size_t)bh * TT + t0 + i) * 256 + tid;
      size_t pq = (size_t)(b * TT + t0 + i) * 3072 + h * 256 + tid;
      cacc += expcG[ga];
      float e = expf(cacc);
      float ei = __builtin_amdgcn_rcpf(e);
      float qv = qkv[pq];
      float kv = qkv[pq + 1024];
      unsigned short wb = f2bf(kv * e);
      unsigned short qb = f2bf(qv * e);
      unsigned short xb = f2bf(kv * ei);
      Wg[ga] = wb;
      Qg[ga] = qb;
      int sw = ((slot ^ (i & 7)) << 3) + byt;
      XB[i * 256 + sw] = xb;
      QW[i * 256 + sw] = qb;
      QW[(i + 64) * 256 + sw] = wb;
      if (i == 63) expcG[ga] = e;
    }
  }
  __syncthreads();

  f32x4 acc[2][4];
#pragma unroll
  for (int tr = 0; tr < 2; ++tr)
#pragma unroll
    for (int tc = 0; tc < 4; ++tc) acc[tr][tc] = (f32x4){0.f, 0.f, 0.f, 0.f};
  const int R0 = w * 32;
#pragma unroll
  for (int kt = 0; kt < 8; ++kt) {
    const int ks = kt * 4 + lg;
    const int ra0 = R0 + ln, ra1 = R0 + 16 + ln;
    bf16x8 a0 = *(const bf16x8*)&QW[ra0 * 256 + ((ks ^ (ra0 & 7)) << 3)];
    bf16x8 a1 = *(const bf16x8*)&QW[ra1 * 256 + ((ks ^ (ra1 & 7)) << 3)];
#pragma unroll
    for (int tc = 0; tc < 4; ++tc) {
      const int br = tc * 16 + ln;
      bf16x8 bf_ = *(const bf16x8*)&XB[br * 256 + ((ks ^ (br & 7)) << 3)];
      acc[0][tc] = __builtin_amdgcn_mfma_f32_16x16x32_bf16(a0, bf_, acc[0][tc], 0, 0, 0);
      acc[1][tc] = __builtin_amdgcn_mfma_f32_16x16x32_bf16(a1, bf_, acc[1][tc], 0, 0, 0);
    }
  }
  const size_t gb = (((size_t)bh * 32 + c) << 12);
  if (w < 2) {
#pragma unroll
    for (int tr = 0; tr < 2; ++tr)
#pragma unroll
      for (int tc = 0; tc < 4; ++tc)
#pragma unroll
        for (int r = 0; r < 4; ++r) {
          int i = R0 + tr * 16 + lg * 4 + r;
          int s = tc * 16 + ln;
          AB[gb + i * 64 + s] = (s <= i) ? f2bf(acc[tr][tc][r]) : (unsigned short)0;
        }
  } else {
#pragma unroll
    for (int tr = 0; tr < 2; ++tr)
#pragma unroll
      for (int tc = 0; tc < 4; ++tc)
#pragma unroll
        for (int r = 0; r < 4; ++r) {
          int i = R0 - 64 + tr * 16 + lg * 4 + r;
          Mb[i * 68 + tc * 16 + ln] = acc[tr][tc][r];
        }
  }
  __syncthreads();

  if (w == 0) {
    float tcol[64];
#pragma unroll
    for (int i = 0; i < 64; ++i) {
      float bi = betaT[(size_t)bh * TT + t0 + i];
      float a_ = (l == i) ? 1.f : 0.f;
#pragma unroll
      for (int s = 0; s < i; ++s)
        a_ = fmaf(-bi * Mb[i * 68 + s], tcol[s], a_);
      tcol[i] = a_;
    }
#pragma unroll
    for (int s = 0; s < 64; ++s) Mb[s * 68 + l] = tcol[s];
  } else {
    const int kk1 = tid - 64;
#pragma unroll 1
    for (int pass = 0; pass < 2; ++pass) {
      if (pass == 1 && kk1 >= 64) break;
      const int k = (pass == 0) ? kk1 : (192 + kk1);
      unsigned short* dst = XTg + ((size_t)bh * 256 + k) * TT + t0;
      const int kslot = k >> 3, kb = k & 7;
#pragma unroll 1
      for (int jq = 0; jq < 8; ++jq) {
        unsigned short e[8];
#pragma unroll
        for (int j = 0; j < 8; ++j) {
          int t = jq * 8 + j;
          e[j] = XB[t * 256 + (((kslot ^ (t & 7)) << 3) + kb)];
        }
        uint4 o;
        o.x = ((unsigned)e[0]) | (((unsigned)e[1]) << 16);
        o.y = ((unsigned)e[2]) | (((unsigned)e[3]) << 16);
        o.z = ((unsigned)e[4]) | (((unsigned)e[5]) << 16);
        o.w = ((unsigned)e[6]) | (((unsigned)e[7]) << 16);
        *(uint4*)(dst + jq * 8) = o;
      }
    }
  }
  __syncthreads();
  {
    const int i = tid >> 2;
    const int sb = (tid & 3) * 16;
#pragma unroll
    for (int mq = 0; mq < 4; ++mq) {
      float v0 = Mb[i * 68 + sb + mq * 4 + 0];
      float v1 = Mb[i * 68 + sb + mq * 4 + 1];
      float v2 = Mb[i * 68 + sb + mq * 4 + 2];
      float v3 = Mb[i * 68 + sb + mq * 4 + 3];
      uint2 p;
      p.x = pack2(v0, v1);
      p.y = pack2(v2, v3);
      *(uint2*)(TinvB + gb + (size_t)i * 64 + sb + mq * 4) = p;
    }
  }
}

// ---------------- phase B: pipelined MFMA chunk scan (R12 structure) -------
__global__ __launch_bounds__(256) void chunk_scan_kernel(
    const unsigned short* __restrict__ Wg, const unsigned short* __restrict__ Qg,
    const unsigned short* __restrict__ XTg, const unsigned short* __restrict__ Tb,
    const unsigned short* __restrict__ Ab, const float* __restrict__ qkv,
    const float* __restrict__ expcG, const float* __restrict__ betaT,
    float* __restrict__ obuf) {
  __shared__ unsigned short ShL[16 * 256];  // [n][k], 16B-slot swizzle ^n
  __shared__ unsigned short SlL[16 * 256];
  __shared__ unsigned short R2bL[16 * 64];  // [n][t], slot swizzle ^(n&7)
  __shared__ unsigned short UbL[16 * 64];
  const int bid = blockIdx.x;
  const int bh = bid & 15, slice = bid >> 4;  // all slices of bh -> same XCD
  const int b = bh >> 2, h = bh & 3;
  const int tid = threadIdx.x;
  const int w = tid >> 6;
  const int l = tid & 63;
  const int ln = l & 15, lg = l >> 4;

  const unsigned short* Wbh = Wg + (size_t)bh * TT * 256;
  const unsigned short* Qbh = Qg + (size_t)bh * TT * 256;
  const unsigned short* XTbh = XTg + (size_t)bh * 256 * TT;
  const unsigned short* Tbh = Tb + (size_t)bh * 32 * 4096;
  const unsigned short* Abh = Ab + (size_t)bh * 32 * 4096;
  const float* betabh = betaT + (size_t)bh * TT;
  const float* ebh = expcG + (size_t)bh * TT * 256;

  f32x4 S0 = {0.f, 0.f, 0.f, 0.f}, S1 = S0, S2 = S0, S3 = S0;

  const int ru_off =
      ln * 64 + ((((w * 2) + (lg >> 1)) ^ (ln & 7)) << 3) + (lg & 1) * 4;

  bf16x8 wA[8], qA[8], wB[8], qB[8];
  float4 vA, bA, vB, bB;

#define LOADWQV(W_, Q_, V_, B_, c_)                                            \
  {                                                                            \
    const int t0_ = (c_) * 64;                                                 \
    _Pragma("unroll") for (int kt = 0; kt < 8; ++kt) {                         \
      const size_t arow =                                                      \
          (size_t)(t0_ + w * 16 + ln) * 256 + kt * 32 + lg * 8;                \
      W_[kt] = *(const bf16x8*)(Wbh + arow);                                   \
      Q_[kt] = *(const bf16x8*)(Qbh + arow);                                   \
    }                                                                          \
    const size_t vrow = (size_t)(b * TT + t0_ + w * 16 + lg * 4) * 3072 +      \
                        2048 + h * 256 + slice * 16 + ln;                      \
    V_.x = siluf(qkv[vrow]);                                                   \
    V_.y = siluf(qkv[vrow + 3072]);                                            \
    V_.z = siluf(qkv[vrow + 2 * 3072]);                                        \
    V_.w = siluf(qkv[vrow + 3 * 3072]);                                        \
    B_ = *(const float4*)(betabh + t0_ + w * 16 + lg * 4);                     \
  }

#define SSTORE(S_, E_, mt_)                                                    \
  {                                                                            \
    S_[0] *= E_.x;                                                             \
    S_[1] *= E_.y;                                                             \
    S_[2] *= E_.z;                                                             \
    S_[3] *= E_.w;                                                             \
    ushort4 hp, lp;                                                            \
    hp.x = f2bf(S_[0]); lp.x = f2bf(S_[0] - bf2f(hp.x));                       \
    hp.y = f2bf(S_[1]); lp.y = f2bf(S_[1] - bf2f(hp.y));                       \
    hp.z = f2bf(S_[2]); lp.z = f2bf(S_[2] - bf2f(hp.z));                       \
    hp.w = f2bf(S_[3]); lp.w = f2bf(S_[3] - bf2f(hp.w));                       \
    const int so_ = ln * 256 +                                                 \
                    ((((w * 8) + (mt_)*2 + (lg >> 1)) ^ ln) << 3) +            \
                    (lg & 1) * 4;                                              \
    *(ushort4*)(&ShL[so_]) = hp;                                               \
    *(ushort4*)(&SlL[so_]) = lp;                                               \
  }

#define CHUNK(Wc, Qc, Vc, Bc, Wn, Qn, Vn, Bn, c_)                              \
  {                                                                            \
    const int c = (c_);                                                        \
    const size_t tb_base = (size_t)c * 4096 + (w * 16 + ln) * 64 + lg * 8;     \
    bf16x8 tf0 = *(const bf16x8*)(Tbh + tb_base);                              \
    bf16x8 tf1 = *(const bf16x8*)(Tbh + tb_base + 32);                         \
    bf16x8 af0 = *(const bf16x8*)(Abh + tb_base);                              \
    bf16x8 af1 = *(const bf16x8*)(Abh + tb_base + 32);                         \
    const size_t xb = (size_t)(w * 64 + ln) * TT + c * 64 + lg * 8;            \
    bf16x8 xf0a = *(const bf16x8*)(XTbh + xb);                                 \
    bf16x8 xf0b = *(const bf16x8*)(XTbh + xb + 32);                            \
    bf16x8 xf1a = *(const bf16x8*)(XTbh + xb + 16 * TT);                       \
    bf16x8 xf1b = *(const bf16x8*)(XTbh + xb + 16 * TT + 32);                  \
    bf16x8 xf2a = *(const bf16x8*)(XTbh + xb + 32 * TT);                       \
    bf16x8 xf2b = *(const bf16x8*)(XTbh + xb + 32 * TT + 32);                  \
    bf16x8 xf3a = *(const bf16x8*)(XTbh + xb + 48 * TT);                       \
    bf16x8 xf3b = *(const bf16x8*)(XTbh + xb + 48 * TT + 32);                  \
    const float* ebase = ebh + (size_t)(c * 64 + 63) * 256 + w * 64 + lg * 4;  \
    float4 eL0 = *(const float4*)(ebase);                                      \
    float4 eL1 = *(const float4*)(ebase + 16);                                 \
    float4 eL2 = *(const float4*)(ebase + 32);                                 \
    float4 eL3 = *(const float4*)(ebase + 48);                                 \
    f32x4 rhs = {0.f, 0.f, 0.f, 0.f}, oq = {0.f, 0.f, 0.f, 0.f};               \
    if (c > 0) {                                                               \
      _Pragma("unroll") for (int kt = 0; kt < 8; ++kt) {                       \
        const int sro = ln * 256 + (((kt * 4 + lg) ^ ln) << 3);                \
        bf16x8 sh = *(const bf16x8*)(&ShL[sro]);                               \
        bf16x8 sl = *(const bf16x8*)(&SlL[sro]);                               \
        rhs = __builtin_amdgcn_mfma_f32_16x16x32_bf16(Wc[kt], sh, rhs, 0, 0, 0); \
        rhs = __builtin_amdgcn_mfma_f32_16x16x32_bf16(Wc[kt], sl, rhs, 0, 0, 0); \
        oq = __builtin_amdgcn_mfma_f32_16x16x32_bf16(Qc[kt], sh, oq, 0, 0, 0); \
        oq = __builtin_amdgcn_mfma_f32_16x16x32_bf16(Qc[kt], sl, oq, 0, 0, 0); \
      }                                                                        \
    }                                                                          \
    if (c + 1 < 32) LOADWQV(Wn, Qn, Vn, Bn, c + 1);                            \
    {                                                                          \
      ushort4 r2p;                                                             \
      r2p.x = f2bf(Bc.x * (Vc.x - rhs[0]));                                    \
      r2p.y = f2bf(Bc.y * (Vc.y - rhs[1]));                                    \
      r2p.z = f2bf(Bc.z * (Vc.z - rhs[2]));                                    \
      r2p.w = f2bf(Bc.w * (Vc.w - rhs[3]));                                    \
      *(ushort4*)(&R2bL[ru_off]) = r2p;                                        \
    }                                                                          \
    LBAR();                                                                    \
    {                                                                          \
      bf16x8 rf0 = *(const bf16x8*)(&R2bL[ln * 64 + (((0 + lg) ^ (ln & 7)) << 3)]); \
      bf16x8 rf1 = *(const bf16x8*)(&R2bL[ln * 64 + (((4 + lg) ^ (ln & 7)) << 3)]); \
      f32x4 u = {0.f, 0.f, 0.f, 0.f};                                          \
      u = __builtin_amdgcn_mfma_f32_16x16x32_bf16(tf0, rf0, u, 0, 0, 0);       \
      u = __builtin_amdgcn_mfma_f32_16x16x32_bf16(tf1, rf1, u, 0, 0, 0);       \
      ushort4 up;                                                              \
      up.x = f2bf(u[0]);                                                       \
      up.y = f2bf(u[1]);                                                       \
      up.z = f2bf(u[2]);                                                       \
      up.w = f2bf(u[3]);                                                       \
      *(ushort4*)(&UbL[ru_off]) = up;                                          \
    }                                                                          \
    LBAR();                                                                    \
    bf16x8 uf0 = *(const bf16x8*)(&UbL[ln * 64 + (((0 + lg) ^ (ln & 7)) << 3)]); \
    bf16x8 uf1 = *(const bf16x8*)(&UbL[ln * 64 + (((4 + lg) ^ (ln & 7)) << 3)]); \
    {                                                                          \
      f32x4 o = oq;                                                            \
      o = __builtin_amdgcn_mfma_f32_16x16x32_bf16(af0, uf0, o, 0, 0, 0);       \
      o = __builtin_amdgcn_mfma_f32_16x16x32_bf16(af1, uf1, o, 0, 0, 0);       \
      const size_t orow =                                                      \
          ((size_t)(b * TT + c * 64 + w * 16 + lg * 4) * HH + h) * 256 +       \
          slice * 16 + ln;                                                     \
      obuf[orow] = o[0];                                                       \
      obuf[orow + HH * 256] = o[1];                                            \
      obuf[orow + 2 * HH * 256] = o[2];                                        \
      obuf[orow + 3 * HH * 256] = o[3];                                        \
    }                                                                          \
    S0 = __builtin_amdgcn_mfma_f32_16x16x32_bf16(xf0a, uf0, S0, 0, 0, 0);      \
    S0 = __builtin_amdgcn_mfma_f32_16x16x32_bf16(xf0b, uf1, S0, 0, 0, 0);      \
    S1 = __builtin_amdgcn_mfma_f32_16x16x32_bf16(xf1a, uf0, S1, 0, 0, 0);      \
    S1 = __builtin_amdgcn_mfma_f32_16x16x32_bf16(xf1b, uf1, S1, 0, 0, 0);      \
    S2 = __builtin_amdgcn_mfma_f32_16x16x32_bf16(xf2a, uf0, S2, 0, 0, 0);      \
    S2 = __builtin_amdgcn_mfma_f32_16x16x32_bf16(xf2b, uf1, S2, 0, 0, 0);      \
    S3 = __builtin_amdgcn_mfma_f32_16x16x32_bf16(xf3a, uf0, S3, 0, 0, 0);      \
    S3 = __builtin_amdgcn_mfma_f32_16x16x32_bf16(xf3b, uf1, S3, 0, 0, 0);      \
    SSTORE(S0, eL0, 0);                                                        \
    SSTORE(S1, eL1, 1);                                                        \
    SSTORE(S2, eL2, 2);                                                        \
    SSTORE(S3, eL3, 3);                                                        \
    LBAR();                                                                    \
  }

  LOADWQV(wA, qA, vA, bA, 0);
  for (int cc = 0; cc < 32; cc += 2) {
    CHUNK(wA, qA, vA, bA, wB, qB, vB, bB, cc);
    CHUNK(wB, qB, vB, bB, wA, qA, vA, bA, cc + 1);
  }
#undef CHUNK
#undef SSTORE
#undef LOADWQV
}

// ---------------- per-head RMSNorm, fused bf16 cast ----------------
__global__ __launch_bounds__(256) void rmsnorm_bf16_kernel(
    const float* __restrict__ o, const float* __restrict__ w,
    unsigned short* __restrict__ out) {
  const int row = blockIdx.x;
  const int l = threadIdx.x & 63;
  const size_t base = (size_t)row * DD + (threadIdx.x >> 6) * 256 + l * 4;
  float4 x = *(const float4*)(o + base);
  float ss = x.x * x.x + x.y * x.y + x.z * x.z + x.w * x.w;
  ss = wave_sum(ss);
  float sc = rsqrtf(ss * (1.f / 256.f) + 1e-5f);
  float4 wv = *(const float4*)(w + l * 4);
  ushort4 o4;
  o4.x = f2bf(x.x * sc * wv.x);
  o4.y = f2bf(x.y * sc * wv.y);
  o4.z = f2bf(x.z * sc * wv.z);
  o4.w = f2bf(x.w * sc * wv.w);
  *(ushort4*)(out + base) = o4;
}

extern "C" void kernel_launch(void* const* d_in, const int* in_sizes, int n_in,
                              void* d_out, int out_size, void* d_ws,
                              size_t ws_size, hipStream_t stream) {
  const float* hidden = (const float*)d_in[0];
  const float* Wq = (const float*)d_in[1];
  const float* Wk = (const float*)d_in[2];
  const float* Wv = (const float*)d_in[3];
  const float* Wa = (const float*)d_in[4];
  const float* Wr = (const float*)d_in[5];
  const float* Wb = (const float*)d_in[6];
  const float* dt = (const float*)d_in[7];
  const float* norm_w = (const float*)d_in[8];
  const float* Wo = (const float*)d_in[9];
  float* out = (float*)d_out;

  const size_t NP = (size_t)BB * TT * DD;  // 8388608
  float* ws = (float*)d_ws;
  float* qkv = ws;            // [8192][3072] (q|k|v)
  float* gbuf = ws + 3 * NP;  // g [bh][T][K]; hlo aliases this pre-routing
  unsigned short* hbf = (unsigned short*)(ws + 4 * NP);
  unsigned short* wT = (unsigned short*)(ws + 4 * NP + NP / 2);
  unsigned short* WT0 = wT;                // Wq^T (q|k|v|o contiguous)
  unsigned short* WT3 = wT + 3 * 1048576;  // Wo^T
  unsigned short* WT4 = wT + 4 * 1048576;  // Wr^T hi
  unsigned short* WT5 = wT + 5 * 1048576;  // Wr^T lo
  float* betaT = ws + 4 * NP + NP / 2 + 3 * 1024 * 1024;
  float* after_beta = betaT + 16 * TT;
  unsigned short* Qg = (unsigned short*)after_beta;
  unsigned short* XTg = Qg + NP;
  unsigned short* Ab = XTg + NP;
  unsigned short* Wgb = hbf;
  unsigned short* Tbb = WT4;
  unsigned short* hlo = (unsigned short*)gbuf;  // dead before routing writes g
  float* rproj = out;

  dim3 bt(256);
  cast2_bf16_kernel<<<8192, 256, 0, stream>>>(hidden, hbf, hlo);
  tcast_all_kernel<<<5120, dim3(32, 8), 0, stream>>>(Wq, Wk, Wv, Wo, Wr, WT0,
                                                     WT4, WT5);

  // fused projections: 1536 qkv blocks + 512 rproj(bt3) blocks, 64KB dyn LDS
  proj_fused_kernel<<<2048, bt, 65536, stream>>>(hbf, hlo, WT0, WT4, WT5, qkv,
                                                 rproj);

  routing_kernel<<<8192, 256, 0, stream>>>(hidden, Wa, Wb, dt, rproj, qkv,
                                           gbuf, betaT);
  phaseA_kernel<<<512, 256, 0, stream>>>(qkv, gbuf, betaT, Tbb, Ab, Wgb, Qg,
                                         XTg);
  chunk_scan_kernel<<<256, 256, 0, stream>>>(Wgb, Qg, XTg, Tbb, Ab, qkv, gbuf,
                                             betaT, out);
  rmsnorm_bf16_kernel<<<8192, 256, 0, stream>>>(out, norm_w, hbf);
  gemm_bt<<<512, bt, 0, stream>>>(hbf, WT3, out, 8192, 1024, 1024);
}